// Round 16
// baseline (10528.669 us; speedup 1.0000x reference)
//
#include <hip/hip_runtime.h>
#include <hip/hip_bf16.h>

// Bidirectional 4-layer residual LSTM encoder, MI355X (gfx950).
// R19: R17 base restored (best passing: 6905 us kernel; R18's merged
// store pass regressed and is reverted) with ONE change: barrier wake-up.
// R17 observed the release via tid==0 then woke 7 waves through a full
// __syncthreads rendezvous (~0.5-1 us/step). R19: after the pre-arrival
// sync (every wave's sc stores already drained by its own vmcnt(0) before
// that sync), lane 0 of EVERY wave polls rel independently (divergent-
// branch spin = whole wave waits), then EACH wave issues its own
// `buffer_inv sc1` (per-wave inv required since no sync orders another
// wave's inv against this wave's loads; inv-only is the cheap half,
// R17-proven). The post-barrier __syncthreads is deleted: all step-t
// gbuf/sh reads completed before the pre-arrival sync, so next-step
// writes are hazard-free.
// R17 structure: XCD-local layer mapping, cached A-loads, coalesced 16B
// sc0sc1 store pass, 2-level agent-atomic tree barrier, weights pinned
// in 128 VGPR/wave.

typedef __bf16 bf16x8 __attribute__((ext_vector_type(8)));
typedef __bf16 bf16x4 __attribute__((ext_vector_type(4)));
typedef float  f32x4  __attribute__((ext_vector_type(4)));
typedef float  f32x2  __attribute__((ext_vector_type(2)));
typedef int    i32x4  __attribute__((ext_vector_type(4)));

constexpr int NB = 64;    // batch
constexpr int NT = 256;   // time
constexpr int ND = 1024;  // embed dim
constexpr int NH = 1024;  // hidden
constexpr int NL = 4;     // layers
constexpr int NG = 4096;  // 4*NH gate rows

// ---- LLC-coherent coalesced store (write-through past L2) ----------------
__device__ __forceinline__ void st_b128_sc(void* p, i32x4 v) {
    asm volatile("global_store_dwordx4 %0, %1, off sc0 sc1" :: "v"(p), "v"(v) : "memory");
}
__device__ __forceinline__ float sigmoidf_fast(float x) {
    return 1.f / (1.f + __expf(-x));
}
__device__ __forceinline__ float tanhf_fast(float x) {
    return 1.f - 2.f / (__expf(2.f * x) + 1.f);   // exact at +-inf, ~1e-6 rel
}

// ---------------------------------------------------------------------------
// Persistent kernel. Grid: 4 layers x 64 cb = 256 blocks (1/CU). Block:
// 512 threads = 8 waves. Wave w: mat = w>>2 (0: Wih, 1: Whh), k0 = (w&3)*256.
// Layer mapping: layer = (bid&7)>>1, cb = ((bid>>3)<<1)|(bid&1) -> layer l
// occupies XCDs {2l, 2l+1} under the bid%8 round-robin dispatch.
// Weight regs: bf16x8 wreg[4 gates][8 ch]. Per step, per dir: acc[4 m][4 n]
// over M=64 batch x N=64 gate-cols, partials -> gbuf (XOR-swizzled) ->
// pointwise LSTM -> LDS staging -> coalesced 16B sc store pass.
// C/D frag (m89): row(batch)=(l>>4)*4+r (+16m), col=l&15.
// Barrier (uint idx): leaves at 32*(bid&15), root at 512, rel at 544.
// Coherence: cached A-reads made safe by per-wave `buffer_inv sc1` after
// each wave's own release poll (stores are sc write-through -> caches
// never dirty; only stale-line invalidation needed).
// ---------------------------------------------------------------------------
__global__ __launch_bounds__(512, 2) void k_lstm(
    const __bf16* __restrict__ xbf,     // [NT][NB][ND]
    const __bf16* __restrict__ Wih,     // [NL][NG][ND] bf16
    const __bf16* __restrict__ Whh,     // [NL][NG][NH] bf16
    const float*  __restrict__ biasc,   // [NL][NG] (b_ih+b_hh)
    __bf16* __restrict__ ring_b,        // [2*NL][2][NB][NH] layer input (bf16)
    float*  __restrict__ ring_f,        // [2*NL][2][NB][NH] layer input (f32)
    __bf16* __restrict__ hbuf,          // [2*NL][2][NB][NH] h ping-pong
    __bf16* __restrict__ outcat,        // [NT][NB][2*NH]
    __bf16* __restrict__ hcat,          // [NL*NB][2*NH] final h
    __bf16* __restrict__ ccat,          // [NL*NB][2*NH] final c
    unsigned* __restrict__ bar)         // barrier state (zeroed per launch)
{
    const int layer = (blockIdx.x & 7) >> 1;                    // XCD-local
    const int cb    = ((blockIdx.x >> 3) << 1) | (blockIdx.x & 1);
    const int tid   = threadIdx.x;
    const int w     = tid >> 6;          // 0..7
    const int mat   = w >> 2;            // 0: x-part (Wih), 1: h-part (Whh)
    const int k0    = (w & 3) * 256;     // K-slice within the 1024 of this mat
    const int lane  = tid & 63;
    const int lrow  = lane & 15;
    const int lk    = (lane >> 4) << 3;
    const int g4r   = (lane >> 4) << 2;  // row base within 16-row frag
    const size_t bh = (size_t)NB * NH;

    // --- persistent weights: 64 rows x 256 K bf16 = 128 VGPRs/wave ---
    bf16x8 wreg[4][8];
    {
        const __bf16* Bp = (mat ? Whh : Wih)
            + ((size_t)layer * NG + cb * 16 + lrow) * 1024 + k0 + lk;
        #pragma unroll
        for (int n = 0; n < 4; ++n)
            #pragma unroll
            for (int ch = 0; ch < 8; ++ch)
                wreg[n][ch] = *(const bf16x8*)(Bp + (size_t)n * NH * 1024 + ch * 32);
    }

    // --- per-thread persistent bias (n = tid&15 is this thread's col) ---
    float bias4[4];
    #pragma unroll
    for (int g = 0; g < 4; ++g)
        bias4[g] = biasc[(size_t)layer * NG + g * NH + cb * 16 + (tid & 15)];

    // --- per-thread persistent c state: [d][cell], cells = rows bp, bp+1 ---
    float c00 = 0.f, c01 = 0.f, c10 = 0.f, c11 = 0.f;

    // transposed partial buffer: [wave][gate][col16][row64], rows XOR-swizzled
    __shared__ __align__(16) float gbuf[8][4][16][64];   // 128 KB
    // output staging for coalesced stores (8 KB)
    __shared__ __align__(16) __bf16 sh_h[64][16];        // h  (bf16)
    __shared__ __align__(16) float  sh_f[64][16];        // residual (f32)
    __shared__ __align__(16) __bf16 sh_c[64][16];        // c  (bf16, final step)

    unsigned* leaf = bar + 32 * (blockIdx.x & 15);
    unsigned* root = bar + 512;
    unsigned* rel  = bar + 544;

    const int n_  = tid & 15;            // this thread's column within cb
    const int col = cb * 16 + n_;
    const int bp  = (tid >> 4) << 1;     // even batch row; cells (bp, bp+1)
    const int sw  = (n_ & 7) << 2;

    for (int gs = 0; gs < NT + NL - 1; ++gs) {
        const int tau = gs - layer;
        if (tau >= 0 && tau < NT) {
            #pragma unroll 1
            for (int d = 0; d < 2; ++d) {
                const int tt = d ? NT - 1 - tau : tau;
                const size_t ul = (size_t)(d * NL + layer);
                const size_t rbase = (ul * 2 + (tau & 1)) * bh;

                // residual inputs: produced last step, inv-fresh -> cached
                // loads issued first; latency hides under the GEMM.
                float inp0, inp1;
                if (layer == 0) {
                    inp0 = (float)xbf[(size_t)tt * NB * ND + (size_t)bp * ND + col];
                    inp1 = (float)xbf[(size_t)tt * NB * ND + (size_t)(bp + 1) * ND + col];
                } else {
                    inp0 = ring_f[rbase + (size_t)bp * NH + col];
                    inp1 = ring_f[rbase + (size_t)(bp + 1) * NH + col];
                }

                const __bf16* Ap;
                if (mat == 0)
                    Ap = (layer == 0) ? (xbf + (size_t)tt * NB * ND)
                                      : (ring_b + rbase);
                else
                    Ap = hbuf + (ul * 2 + ((tau + 1) & 1)) * bh;
                Ap += (size_t)lrow * 1024 + k0 + lk;

                // cached A-loads: this XCD's L2 serves the 32 co-located
                // blocks of this layer; compiler software-pipelines chunks.
                f32x4 acc[4][4] = {};   // [m][gate]
                #pragma unroll
                for (int ch = 0; ch < 8; ++ch) {
                    bf16x8 av[4];
                    #pragma unroll
                    for (int m = 0; m < 4; ++m)
                        av[m] = *(const bf16x8*)(Ap + (size_t)m * 16384 + ch * 32);
                    #pragma unroll
                    for (int n = 0; n < 4; ++n)
                        #pragma unroll
                        for (int m = 0; m < 4; ++m)
                            acc[m][n] = __builtin_amdgcn_mfma_f32_16x16x32_bf16(
                                av[m], wreg[n][ch], acc[m][n], 0, 0, 0);
                }

                // partials -> LDS as f32x4 (4 consecutive batch rows), swizzled
                #pragma unroll
                for (int n = 0; n < 4; ++n)
                    #pragma unroll
                    for (int m = 0; m < 4; ++m) {
                        const int row = (m * 16 + g4r) ^ ((lrow & 7) << 2);
                        *(f32x4*)&gbuf[w][n][lrow][row] = acc[m][n];
                    }
                __syncthreads();

                // fused LSTM pointwise: 2 adjacent cells/thread, f32x2 reduce
                {
                    const int swb = bp ^ sw;     // even; pair (swb, swb+1)
                    float g0[4], g1[4];
                    #pragma unroll
                    for (int g = 0; g < 4; ++g) {
                        float s0 = bias4[g], s1 = bias4[g];
                        #pragma unroll
                        for (int q = 0; q < 8; ++q) {
                            const f32x2 v = *(const f32x2*)&gbuf[q][g][n_][swb];
                            s0 += v[0]; s1 += v[1];
                        }
                        g0[g] = s0; g1[g] = s1;
                    }
                    const float cp0 = d ? c10 : c00;
                    const float cp1 = d ? c11 : c01;
                    const float si0 = sigmoidf_fast(g0[0]);
                    const float sf0 = sigmoidf_fast(g0[1]);
                    const float so0 = sigmoidf_fast(g0[3]);
                    const float tg0 = tanhf_fast(g0[2]);
                    const float cn0 = sf0 * cp0 + si0 * tg0;
                    const float hn0 = so0 * tanhf_fast(cn0);
                    const float si1 = sigmoidf_fast(g1[0]);
                    const float sf1 = sigmoidf_fast(g1[1]);
                    const float so1 = sigmoidf_fast(g1[3]);
                    const float tg1 = tanhf_fast(g1[2]);
                    const float cn1 = sf1 * cp1 + si1 * tg1;
                    const float hn1 = so1 * tanhf_fast(cn1);
                    if (d) { c10 = cn0; c11 = cn1; }
                    else   { c00 = cn0; c01 = cn1; }

                    // stage to LDS (coalesced global store pass follows)
                    sh_h[bp][n_]     = (__bf16)hn0;
                    sh_h[bp + 1][n_] = (__bf16)hn1;
                    sh_f[bp][n_]     = inp0 + hn0;
                    sh_f[bp + 1][n_] = inp1 + hn1;
                    if (tau == NT - 1) {
                        sh_c[bp][n_]     = (__bf16)cn0;
                        sh_c[bp + 1][n_] = (__bf16)cn1;
                    }
                }
                __syncthreads();

                // ---- coalesced 16B sc store pass ----
                if (tid < 128) {
                    const int r = tid >> 1, sg = tid & 1;
                    const i32x4 v = *(const i32x4*)&sh_h[r][sg * 8];
                    st_b128_sc(hbuf + rbase + (size_t)r * NH + cb * 16 + sg * 8, v);
                    if (tau == NT - 1) {
                        st_b128_sc(hcat + ((size_t)layer * NB + r) * 2048
                                        + (size_t)d * NH + cb * 16 + sg * 8, v);
                    }
                } else if (tid < 384) {
                    if (layer < NL - 1) {
                        const int t2 = tid - 128;
                        const int r = t2 >> 2, sg = t2 & 3;
                        const i32x4 v = *(const i32x4*)&sh_f[r][sg * 4];
                        st_b128_sc(ring_f + ((ul + 1) * 2 + (tau & 1)) * bh
                                          + (size_t)r * NH + cb * 16 + sg * 4, v);
                    }
                    if (tau == NT - 1 && tid < 256) {
                        const int t2 = tid - 128;
                        const int r = t2 >> 1, sg = t2 & 1;
                        const i32x4 v = *(const i32x4*)&sh_c[r][sg * 8];
                        st_b128_sc(ccat + ((size_t)layer * NB + r) * 2048
                                        + (size_t)d * NH + cb * 16 + sg * 8, v);
                    }
                } else {
                    const int t3 = tid - 384;
                    const int r = t3 >> 1, sg = t3 & 1;
                    bf16x8 o;
                    #pragma unroll
                    for (int j = 0; j < 8; ++j) o[j] = (__bf16)sh_f[r][sg * 8 + j];
                    const i32x4 v = __builtin_bit_cast(i32x4, o);
                    if (layer < NL - 1)
                        st_b128_sc(ring_b + ((ul + 1) * 2 + (tau & 1)) * bh
                                          + (size_t)r * NH + cb * 16 + sg * 8, v);
                    else
                        st_b128_sc(outcat + ((size_t)tt * NB + r) * 2048
                                          + (size_t)d * NH + cb * 16 + sg * 8, v);
                }

                if (d == 1)   // drain asm sc stores once per step, pre-barrier
                    asm volatile("s_waitcnt vmcnt(0)" ::: "memory");
                __syncthreads();
            }
        }

        // ---- grid barrier: tree arrival + PER-WAVE release poll ----
        // Pre-arrival __syncthreads (above, end of d1) guarantees every
        // wave's sc stores were drained (each wave ran its own vmcnt(0)
        // before the sync). Each wave then observes rel independently and
        // issues its own buffer_inv; no post-barrier rendezvous needed
        // (all step-t LDS reads completed before the pre-arrival sync).
        if (gs < NT + NL - 2) {
            const unsigned e1 = (unsigned)(gs + 1);
            if (tid == 0) {
                const unsigned old = __hip_atomic_fetch_add(
                    leaf, 1u, __ATOMIC_RELAXED, __HIP_MEMORY_SCOPE_AGENT);
                if (old == 16u * e1 - 1u) {
                    const unsigned r = __hip_atomic_fetch_add(
                        root, 1u, __ATOMIC_RELAXED, __HIP_MEMORY_SCOPE_AGENT);
                    if (r == 16u * e1 - 1u)
                        __hip_atomic_store(rel, e1, __ATOMIC_RELAXED,
                                           __HIP_MEMORY_SCOPE_AGENT);
                }
            }
            if (lane == 0) {   // every wave spins (divergent branch = wave waits)
                while (__hip_atomic_load(rel, __ATOMIC_RELAXED,
                                         __HIP_MEMORY_SCOPE_AGENT) < e1)
                    __builtin_amdgcn_s_sleep(2);
            }
            // per-wave acquire: invalidate stale L1/L2 lines (caches never
            // dirty - all stores are sc0sc1 write-through).
            asm volatile("buffer_inv sc1" ::: "memory");
        }
    }
}

// ---------------------------------------------------------------------------
// Projection GEMM: Dst = A[M][2048] @ W[1024][2048]^T + bias.
// mode 0: A rows are (t*NB+b), write Dst[(b*NT+t)*NH + col]. mode 1: direct.
// ---------------------------------------------------------------------------
__global__ __launch_bounds__(256) void k_proj(
    const __bf16* __restrict__ A, const __bf16* __restrict__ W,
    const float* __restrict__ bias, float* __restrict__ Dst,
    int M, int mode)
{
    const int nblk = blockIdx.x & 15;
    const int mblk = blockIdx.x >> 4;
    const int tid  = threadIdx.x;
    const int w    = tid >> 6;
    const int lane = tid & 63;
    const int lrow = lane & 15;
    const int lk   = (lane >> 4) << 3;
    const int n0   = nblk * 64 + w * 16;
    const int m0   = mblk * 64;

    f32x4 acc[4] = {};
    #pragma unroll 2
    for (int k0 = 0; k0 < 2048; k0 += 32) {
        const int kc = k0 + lk;
        const bf16x8 bv = *(const bf16x8*)(W + (size_t)(n0 + lrow) * 2048 + kc);
        #pragma unroll
        for (int m = 0; m < 4; ++m) {
            const bf16x8 av = *(const bf16x8*)(A + (size_t)(m0 + m * 16 + lrow) * 2048 + kc);
            acc[m] = __builtin_amdgcn_mfma_f32_16x16x32_bf16(av, bv, acc[m], 0, 0, 0);
        }
    }
    #pragma unroll
    for (int m = 0; m < 4; ++m) {
        #pragma unroll
        for (int r = 0; r < 4; ++r) {
            const int row = m0 + m * 16 + ((lane >> 4) << 2) + r;
            const int col = n0 + lrow;
            const float v = acc[m][r] + bias[col];
            if (mode == 0) {
                const int tt = row >> 6, bb = row & 63;
                Dst[((size_t)bb * NT + tt) * NH + col] = v;
            } else {
                Dst[(size_t)row * NH + col] = v;
            }
        }
    }
}

__global__ void k_embed(const int* __restrict__ enc, const float* __restrict__ emb,
                        __bf16* __restrict__ xbf)
{
    const int r = blockIdx.x;          // t*NB + b
    const int t = r >> 6;
    const int b = r & 63;
    const int id = enc[b * NT + t];
    const float4 v = ((const float4*)(emb + (size_t)id * ND))[threadIdx.x];
    bf16x4 o;
    o[0] = (__bf16)v.x; o[1] = (__bf16)v.y; o[2] = (__bf16)v.z; o[3] = (__bf16)v.w;
    ((bf16x4*)(xbf + (size_t)r * ND))[threadIdx.x] = o;
}

__global__ void k_cvt(const float* __restrict__ src, __bf16* __restrict__ dst, size_t n4)
{
    size_t i = (size_t)blockIdx.x * blockDim.x + threadIdx.x;
    const size_t stride = (size_t)gridDim.x * blockDim.x;
    for (; i < n4; i += stride) {
        const float4 v = ((const float4*)src)[i];
        bf16x4 o;
        o[0] = (__bf16)v.x; o[1] = (__bf16)v.y; o[2] = (__bf16)v.z; o[3] = (__bf16)v.w;
        ((bf16x4*)dst)[i] = o;
    }
}

__global__ void k_bias(const float* __restrict__ a, const float* __restrict__ b,
                       float* __restrict__ o, int n)
{
    const int i = blockIdx.x * blockDim.x + threadIdx.x;
    if (i < n) o[i] = a[i] + b[i];
}

extern "C" void kernel_launch(void* const* d_in, const int* in_sizes, int n_in,
                              void* d_out, int out_size, void* d_ws, size_t ws_size,
                              hipStream_t stream)
{
    const int*   enc   = (const int*)  d_in[0];
    const float* emb   = (const float*)d_in[1];
    const float* Wih_f = (const float*)d_in[2];
    const float* Whh_f = (const float*)d_in[3];
    const float* bih   = (const float*)d_in[4];
    const float* bhh   = (const float*)d_in[5];
    const float* Wo_f  = (const float*)d_in[6];
    const float* bo    = (const float*)d_in[7];
    const float* Wh_f  = (const float*)d_in[8];
    const float* bh    = (const float*)d_in[9];
    const float* Wc_f  = (const float*)d_in[10];
    const float* bc    = (const float*)d_in[11];
    float* out = (float*)d_out;

    char* ws = (char*)d_ws;
    size_t off = 0;
    auto alloc = [&](size_t bytes) -> char* {
        off = (off + 255) & ~(size_t)255;
        char* p = ws + off;
        off += bytes;
        return p;
    };
    __bf16* Wih_b  = (__bf16*)alloc((size_t)NL * NG * ND * 2);
    __bf16* Whh_b  = (__bf16*)alloc((size_t)NL * NG * NH * 2);
    __bf16* Wo_b   = (__bf16*)alloc((size_t)NH * 2 * NH * 2);
    __bf16* Wh_b   = (__bf16*)alloc((size_t)NH * 2 * NH * 2);
    __bf16* Wc_b   = (__bf16*)alloc((size_t)NH * 2 * NH * 2);
    float*  biasc  = (float*) alloc((size_t)NL * NG * 4);
    __bf16* xbf    = (__bf16*)alloc((size_t)NT * NB * ND * 2);
    __bf16* ring_b = (__bf16*)alloc((size_t)2 * NL * 2 * NB * NH * 2);
    float*  ring_f = (float*) alloc((size_t)2 * NL * 2 * NB * NH * 4);
    __bf16* hbuf   = (__bf16*)alloc((size_t)2 * NL * 2 * NB * NH * 2);
    __bf16* outcat = (__bf16*)alloc((size_t)NT * NB * 2 * NH * 2);
    __bf16* hcat   = (__bf16*)alloc((size_t)NL * NB * 2 * NH * 2);
    __bf16* ccat   = (__bf16*)alloc((size_t)NL * NB * 2 * NH * 2);
    unsigned* bar  = (unsigned*)alloc(4096);

    auto launch_cvt = [&](const float* s, __bf16* d, size_t n) {
        size_t n4 = n / 4;
        int blocks = (int)((n4 + 255) / 256);
        if (blocks > 2048) blocks = 2048;
        k_cvt<<<blocks, 256, 0, stream>>>(s, d, n4);
    };
    launch_cvt(Wih_f, Wih_b, (size_t)NL * NG * ND);
    launch_cvt(Whh_f, Whh_b, (size_t)NL * NG * NH);
    launch_cvt(Wo_f,  Wo_b,  (size_t)2 * NH * NH);
    launch_cvt(Wh_f,  Wh_b,  (size_t)2 * NH * NH);
    launch_cvt(Wc_f,  Wc_b,  (size_t)2 * NH * NH);
    k_bias<<<(NL * NG) / 256, 256, 0, stream>>>(bih, bhh, biasc, NL * NG);
    k_embed<<<NT * NB, 256, 0, stream>>>(enc, emb, xbf);
    // h state + barrier counters must be zeroed EVERY launch (graph replays
    // leave final state; barrier epochs are monotonic within one launch).
    hipMemsetAsync(hbuf, 0, (size_t)2 * NL * 2 * NB * NH * 2, stream);
    hipMemsetAsync(bar, 0, 4096, stream);

    void* kargs[] = {
        (void*)&xbf, (void*)&Wih_b, (void*)&Whh_b, (void*)&biasc,
        (void*)&ring_b, (void*)&ring_f, (void*)&hbuf,
        (void*)&outcat, (void*)&hcat, (void*)&ccat, (void*)&bar };
    hipLaunchCooperativeKernel((const void*)k_lstm, dim3(256), dim3(512),
                               kargs, 0, stream);

    k_proj<<<(NT * NB / 64) * 16, 256, 0, stream>>>(outcat, Wo_b, bo, out, NT * NB, 0);
    k_proj<<<(NL * NB / 64) * 16, 256, 0, stream>>>(hcat, Wh_b, bh,
        out + (size_t)NB * NT * NH, NL * NB, 1);
    k_proj<<<(NL * NB / 64) * 16, 256, 0, stream>>>(ccat, Wc_b, bc,
        out + (size_t)NB * NT * NH + (size_t)NL * NB * NH, NL * NB, 1);
}

// Round 17
// 7460.423 us; speedup vs baseline: 1.4113x; 1.4113x over previous
//
#include <hip/hip_runtime.h>
#include <hip/hip_bf16.h>

// Bidirectional 4-layer residual LSTM encoder, MI355X (gfx950).
// R20 = R17 EXACT REVERT (best measured: 6905 us kernel / 7535 us total).
// R18 (merged store pass, +LDS) and R19 (per-wave poll + per-wave
// buffer_inv) both regressed; 8 redundant per-wave cache-invalidates
// serialize at the L2 interface. R17's single-poller + __syncthreads +
// ONE buffer_inv sc1 per block is the proven optimum of this structure.
// Structure: persistent cooperative kernel, weights pinned in 128 VGPR/
// wave (64 MB chip-wide, read once), XCD-local layer mapping
// (layer=(bid&7)>>1 -> each layer on 2 XCDs), cached A-loads (XCD L2
// dedup), per-step coalesced 16B sc0sc1 write-through store pass,
// 2-level agent-atomic tree barrier, acquire-only buffer_inv after the
// release poll (caches never dirty -> no wbl2 needed).

typedef __bf16 bf16x8 __attribute__((ext_vector_type(8)));
typedef __bf16 bf16x4 __attribute__((ext_vector_type(4)));
typedef float  f32x4  __attribute__((ext_vector_type(4)));
typedef float  f32x2  __attribute__((ext_vector_type(2)));
typedef int    i32x4  __attribute__((ext_vector_type(4)));

constexpr int NB = 64;    // batch
constexpr int NT = 256;   // time
constexpr int ND = 1024;  // embed dim
constexpr int NH = 1024;  // hidden
constexpr int NL = 4;     // layers
constexpr int NG = 4096;  // 4*NH gate rows

// ---- LLC-coherent coalesced store (write-through past L2) ----------------
__device__ __forceinline__ void st_b128_sc(void* p, i32x4 v) {
    asm volatile("global_store_dwordx4 %0, %1, off sc0 sc1" :: "v"(p), "v"(v) : "memory");
}
__device__ __forceinline__ float sigmoidf_fast(float x) {
    return 1.f / (1.f + __expf(-x));
}
__device__ __forceinline__ float tanhf_fast(float x) {
    return 1.f - 2.f / (__expf(2.f * x) + 1.f);   // exact at +-inf, ~1e-6 rel
}

// ---------------------------------------------------------------------------
// Persistent kernel. Grid: 4 layers x 64 cb = 256 blocks (1/CU). Block:
// 512 threads = 8 waves. Wave w: mat = w>>2 (0: Wih, 1: Whh), k0 = (w&3)*256.
// Layer mapping: layer = (bid&7)>>1, cb = ((bid>>3)<<1)|(bid&1) -> layer l
// occupies XCDs {2l, 2l+1} under the bid%8 round-robin dispatch.
// Weight regs: bf16x8 wreg[4 gates][8 ch]. Per step, per dir: acc[4 m][4 n]
// over M=64 batch x N=64 gate-cols, partials -> gbuf (XOR-swizzled) ->
// pointwise LSTM -> LDS staging -> coalesced 16B sc store pass.
// C/D frag (m89): row(batch)=(l>>4)*4+r (+16m), col=l&15.
// Barrier (uint idx): leaves at 32*(bid&15), root at 512, rel at 544.
// Coherence: cached A-reads made safe by `buffer_inv sc1` after the
// barrier poll (stores are sc write-through -> caches never dirty; only
// stale-line invalidation needed).
// ---------------------------------------------------------------------------
__global__ __launch_bounds__(512, 2) void k_lstm(
    const __bf16* __restrict__ xbf,     // [NT][NB][ND]
    const __bf16* __restrict__ Wih,     // [NL][NG][ND] bf16
    const __bf16* __restrict__ Whh,     // [NL][NG][NH] bf16
    const float*  __restrict__ biasc,   // [NL][NG] (b_ih+b_hh)
    __bf16* __restrict__ ring_b,        // [2*NL][2][NB][NH] layer input (bf16)
    float*  __restrict__ ring_f,        // [2*NL][2][NB][NH] layer input (f32)
    __bf16* __restrict__ hbuf,          // [2*NL][2][NB][NH] h ping-pong
    __bf16* __restrict__ outcat,        // [NT][NB][2*NH]
    __bf16* __restrict__ hcat,          // [NL*NB][2*NH] final h
    __bf16* __restrict__ ccat,          // [NL*NB][2*NH] final c
    unsigned* __restrict__ bar)         // barrier state (zeroed per launch)
{
    const int layer = (blockIdx.x & 7) >> 1;                    // XCD-local
    const int cb    = ((blockIdx.x >> 3) << 1) | (blockIdx.x & 1);
    const int tid   = threadIdx.x;
    const int w     = tid >> 6;          // 0..7
    const int mat   = w >> 2;            // 0: x-part (Wih), 1: h-part (Whh)
    const int k0    = (w & 3) * 256;     // K-slice within the 1024 of this mat
    const int lane  = tid & 63;
    const int lrow  = lane & 15;
    const int lk    = (lane >> 4) << 3;
    const int g4r   = (lane >> 4) << 2;  // row base within 16-row frag
    const size_t bh = (size_t)NB * NH;

    // --- persistent weights: 64 rows x 256 K bf16 = 128 VGPRs/wave ---
    bf16x8 wreg[4][8];
    {
        const __bf16* Bp = (mat ? Whh : Wih)
            + ((size_t)layer * NG + cb * 16 + lrow) * 1024 + k0 + lk;
        #pragma unroll
        for (int n = 0; n < 4; ++n)
            #pragma unroll
            for (int ch = 0; ch < 8; ++ch)
                wreg[n][ch] = *(const bf16x8*)(Bp + (size_t)n * NH * 1024 + ch * 32);
    }

    // --- per-thread persistent bias (n = tid&15 is this thread's col) ---
    float bias4[4];
    #pragma unroll
    for (int g = 0; g < 4; ++g)
        bias4[g] = biasc[(size_t)layer * NG + g * NH + cb * 16 + (tid & 15)];

    // --- per-thread persistent c state: [d][cell], cells = rows bp, bp+1 ---
    float c00 = 0.f, c01 = 0.f, c10 = 0.f, c11 = 0.f;

    // transposed partial buffer: [wave][gate][col16][row64], rows XOR-swizzled
    __shared__ __align__(16) float gbuf[8][4][16][64];   // 128 KB
    // output staging for coalesced stores (8 KB)
    __shared__ __align__(16) __bf16 sh_h[64][16];        // h  (bf16)
    __shared__ __align__(16) float  sh_f[64][16];        // residual (f32)
    __shared__ __align__(16) __bf16 sh_c[64][16];        // c  (bf16, final step)

    unsigned* leaf = bar + 32 * (blockIdx.x & 15);
    unsigned* root = bar + 512;
    unsigned* rel  = bar + 544;

    const int n_  = tid & 15;            // this thread's column within cb
    const int col = cb * 16 + n_;
    const int bp  = (tid >> 4) << 1;     // even batch row; cells (bp, bp+1)
    const int sw  = (n_ & 7) << 2;

    for (int gs = 0; gs < NT + NL - 1; ++gs) {
        const int tau = gs - layer;
        if (tau >= 0 && tau < NT) {
            #pragma unroll 1
            for (int d = 0; d < 2; ++d) {
                const int tt = d ? NT - 1 - tau : tau;
                const size_t ul = (size_t)(d * NL + layer);
                const size_t rbase = (ul * 2 + (tau & 1)) * bh;

                // residual inputs: produced last step, inv-fresh -> cached
                // loads issued first; latency hides under the GEMM.
                float inp0, inp1;
                if (layer == 0) {
                    inp0 = (float)xbf[(size_t)tt * NB * ND + (size_t)bp * ND + col];
                    inp1 = (float)xbf[(size_t)tt * NB * ND + (size_t)(bp + 1) * ND + col];
                } else {
                    inp0 = ring_f[rbase + (size_t)bp * NH + col];
                    inp1 = ring_f[rbase + (size_t)(bp + 1) * NH + col];
                }

                const __bf16* Ap;
                if (mat == 0)
                    Ap = (layer == 0) ? (xbf + (size_t)tt * NB * ND)
                                      : (ring_b + rbase);
                else
                    Ap = hbuf + (ul * 2 + ((tau + 1) & 1)) * bh;
                Ap += (size_t)lrow * 1024 + k0 + lk;

                // cached A-loads: this XCD's L2 serves the 32 co-located
                // blocks of this layer; compiler software-pipelines chunks.
                f32x4 acc[4][4] = {};   // [m][gate]
                #pragma unroll
                for (int ch = 0; ch < 8; ++ch) {
                    bf16x8 av[4];
                    #pragma unroll
                    for (int m = 0; m < 4; ++m)
                        av[m] = *(const bf16x8*)(Ap + (size_t)m * 16384 + ch * 32);
                    #pragma unroll
                    for (int n = 0; n < 4; ++n)
                        #pragma unroll
                        for (int m = 0; m < 4; ++m)
                            acc[m][n] = __builtin_amdgcn_mfma_f32_16x16x32_bf16(
                                av[m], wreg[n][ch], acc[m][n], 0, 0, 0);
                }

                // partials -> LDS as f32x4 (4 consecutive batch rows), swizzled
                #pragma unroll
                for (int n = 0; n < 4; ++n)
                    #pragma unroll
                    for (int m = 0; m < 4; ++m) {
                        const int row = (m * 16 + g4r) ^ ((lrow & 7) << 2);
                        *(f32x4*)&gbuf[w][n][lrow][row] = acc[m][n];
                    }
                __syncthreads();

                // fused LSTM pointwise: 2 adjacent cells/thread, f32x2 reduce
                {
                    const int swb = bp ^ sw;     // even; pair (swb, swb+1)
                    float g0[4], g1[4];
                    #pragma unroll
                    for (int g = 0; g < 4; ++g) {
                        float s0 = bias4[g], s1 = bias4[g];
                        #pragma unroll
                        for (int q = 0; q < 8; ++q) {
                            const f32x2 v = *(const f32x2*)&gbuf[q][g][n_][swb];
                            s0 += v[0]; s1 += v[1];
                        }
                        g0[g] = s0; g1[g] = s1;
                    }
                    const float cp0 = d ? c10 : c00;
                    const float cp1 = d ? c11 : c01;
                    const float si0 = sigmoidf_fast(g0[0]);
                    const float sf0 = sigmoidf_fast(g0[1]);
                    const float so0 = sigmoidf_fast(g0[3]);
                    const float tg0 = tanhf_fast(g0[2]);
                    const float cn0 = sf0 * cp0 + si0 * tg0;
                    const float hn0 = so0 * tanhf_fast(cn0);
                    const float si1 = sigmoidf_fast(g1[0]);
                    const float sf1 = sigmoidf_fast(g1[1]);
                    const float so1 = sigmoidf_fast(g1[3]);
                    const float tg1 = tanhf_fast(g1[2]);
                    const float cn1 = sf1 * cp1 + si1 * tg1;
                    const float hn1 = so1 * tanhf_fast(cn1);
                    if (d) { c10 = cn0; c11 = cn1; }
                    else   { c00 = cn0; c01 = cn1; }

                    // stage to LDS (coalesced global store pass follows)
                    sh_h[bp][n_]     = (__bf16)hn0;
                    sh_h[bp + 1][n_] = (__bf16)hn1;
                    sh_f[bp][n_]     = inp0 + hn0;
                    sh_f[bp + 1][n_] = inp1 + hn1;
                    if (tau == NT - 1) {
                        sh_c[bp][n_]     = (__bf16)cn0;
                        sh_c[bp + 1][n_] = (__bf16)cn1;
                    }
                }
                __syncthreads();

                // ---- coalesced 16B sc store pass ----
                if (tid < 128) {
                    const int r = tid >> 1, sg = tid & 1;
                    const i32x4 v = *(const i32x4*)&sh_h[r][sg * 8];
                    st_b128_sc(hbuf + rbase + (size_t)r * NH + cb * 16 + sg * 8, v);
                    if (tau == NT - 1) {
                        st_b128_sc(hcat + ((size_t)layer * NB + r) * 2048
                                        + (size_t)d * NH + cb * 16 + sg * 8, v);
                    }
                } else if (tid < 384) {
                    if (layer < NL - 1) {
                        const int t2 = tid - 128;
                        const int r = t2 >> 2, sg = t2 & 3;
                        const i32x4 v = *(const i32x4*)&sh_f[r][sg * 4];
                        st_b128_sc(ring_f + ((ul + 1) * 2 + (tau & 1)) * bh
                                          + (size_t)r * NH + cb * 16 + sg * 4, v);
                    }
                    if (tau == NT - 1 && tid < 256) {
                        const int t2 = tid - 128;
                        const int r = t2 >> 1, sg = t2 & 1;
                        const i32x4 v = *(const i32x4*)&sh_c[r][sg * 8];
                        st_b128_sc(ccat + ((size_t)layer * NB + r) * 2048
                                        + (size_t)d * NH + cb * 16 + sg * 8, v);
                    }
                } else {
                    const int t3 = tid - 384;
                    const int r = t3 >> 1, sg = t3 & 1;
                    bf16x8 o;
                    #pragma unroll
                    for (int j = 0; j < 8; ++j) o[j] = (__bf16)sh_f[r][sg * 8 + j];
                    const i32x4 v = __builtin_bit_cast(i32x4, o);
                    if (layer < NL - 1)
                        st_b128_sc(ring_b + ((ul + 1) * 2 + (tau & 1)) * bh
                                          + (size_t)r * NH + cb * 16 + sg * 8, v);
                    else
                        st_b128_sc(outcat + ((size_t)tt * NB + r) * 2048
                                          + (size_t)d * NH + cb * 16 + sg * 8, v);
                }

                if (d == 1)   // drain asm sc stores once per step, pre-barrier
                    asm volatile("s_waitcnt vmcnt(0)" ::: "memory");
                __syncthreads();
            }
        }

        // ---- grid barrier: two-level agent-atomic tree (R9/R12-proven) ----
        if (gs < NT + NL - 2) {
            __syncthreads();
            if (tid == 0) {
                const unsigned e1 = (unsigned)(gs + 1);
                const unsigned old = __hip_atomic_fetch_add(
                    leaf, 1u, __ATOMIC_RELAXED, __HIP_MEMORY_SCOPE_AGENT);
                if (old == 16u * e1 - 1u) {
                    const unsigned r = __hip_atomic_fetch_add(
                        root, 1u, __ATOMIC_RELAXED, __HIP_MEMORY_SCOPE_AGENT);
                    if (r == 16u * e1 - 1u)
                        __hip_atomic_store(rel, e1, __ATOMIC_RELAXED,
                                           __HIP_MEMORY_SCOPE_AGENT);
                }
                while (__hip_atomic_load(rel, __ATOMIC_RELAXED,
                                         __HIP_MEMORY_SCOPE_AGENT) < e1)
                    __builtin_amdgcn_s_sleep(2);
                // acquire-only: invalidate stale L1/L2 lines (caches are
                // never dirty - all stores are sc0sc1 write-through), so
                // the wbl2 half of __threadfence is unnecessary.
                asm volatile("buffer_inv sc1" ::: "memory");
            }
            __syncthreads();
        }
    }
}

// ---------------------------------------------------------------------------
// Projection GEMM: Dst = A[M][2048] @ W[1024][2048]^T + bias.
// mode 0: A rows are (t*NB+b), write Dst[(b*NT+t)*NH + col]. mode 1: direct.
// ---------------------------------------------------------------------------
__global__ __launch_bounds__(256) void k_proj(
    const __bf16* __restrict__ A, const __bf16* __restrict__ W,
    const float* __restrict__ bias, float* __restrict__ Dst,
    int M, int mode)
{
    const int nblk = blockIdx.x & 15;
    const int mblk = blockIdx.x >> 4;
    const int tid  = threadIdx.x;
    const int w    = tid >> 6;
    const int lane = tid & 63;
    const int lrow = lane & 15;
    const int lk   = (lane >> 4) << 3;
    const int n0   = nblk * 64 + w * 16;
    const int m0   = mblk * 64;

    f32x4 acc[4] = {};
    #pragma unroll 2
    for (int k0 = 0; k0 < 2048; k0 += 32) {
        const int kc = k0 + lk;
        const bf16x8 bv = *(const bf16x8*)(W + (size_t)(n0 + lrow) * 2048 + kc);
        #pragma unroll
        for (int m = 0; m < 4; ++m) {
            const bf16x8 av = *(const bf16x8*)(A + (size_t)(m0 + m * 16 + lrow) * 2048 + kc);
            acc[m] = __builtin_amdgcn_mfma_f32_16x16x32_bf16(av, bv, acc[m], 0, 0, 0);
        }
    }
    #pragma unroll
    for (int m = 0; m < 4; ++m) {
        #pragma unroll
        for (int r = 0; r < 4; ++r) {
            const int row = m0 + m * 16 + ((lane >> 4) << 2) + r;
            const int col = n0 + lrow;
            const float v = acc[m][r] + bias[col];
            if (mode == 0) {
                const int tt = row >> 6, bb = row & 63;
                Dst[((size_t)bb * NT + tt) * NH + col] = v;
            } else {
                Dst[(size_t)row * NH + col] = v;
            }
        }
    }
}

__global__ void k_embed(const int* __restrict__ enc, const float* __restrict__ emb,
                        __bf16* __restrict__ xbf)
{
    const int r = blockIdx.x;          // t*NB + b
    const int t = r >> 6;
    const int b = r & 63;
    const int id = enc[b * NT + t];
    const float4 v = ((const float4*)(emb + (size_t)id * ND))[threadIdx.x];
    bf16x4 o;
    o[0] = (__bf16)v.x; o[1] = (__bf16)v.y; o[2] = (__bf16)v.z; o[3] = (__bf16)v.w;
    ((bf16x4*)(xbf + (size_t)r * ND))[threadIdx.x] = o;
}

__global__ void k_cvt(const float* __restrict__ src, __bf16* __restrict__ dst, size_t n4)
{
    size_t i = (size_t)blockIdx.x * blockDim.x + threadIdx.x;
    const size_t stride = (size_t)gridDim.x * blockDim.x;
    for (; i < n4; i += stride) {
        const float4 v = ((const float4*)src)[i];
        bf16x4 o;
        o[0] = (__bf16)v.x; o[1] = (__bf16)v.y; o[2] = (__bf16)v.z; o[3] = (__bf16)v.w;
        ((bf16x4*)dst)[i] = o;
    }
}

__global__ void k_bias(const float* __restrict__ a, const float* __restrict__ b,
                       float* __restrict__ o, int n)
{
    const int i = blockIdx.x * blockDim.x + threadIdx.x;
    if (i < n) o[i] = a[i] + b[i];
}

extern "C" void kernel_launch(void* const* d_in, const int* in_sizes, int n_in,
                              void* d_out, int out_size, void* d_ws, size_t ws_size,
                              hipStream_t stream)
{
    const int*   enc   = (const int*)  d_in[0];
    const float* emb   = (const float*)d_in[1];
    const float* Wih_f = (const float*)d_in[2];
    const float* Whh_f = (const float*)d_in[3];
    const float* bih   = (const float*)d_in[4];
    const float* bhh   = (const float*)d_in[5];
    const float* Wo_f  = (const float*)d_in[6];
    const float* bo    = (const float*)d_in[7];
    const float* Wh_f  = (const float*)d_in[8];
    const float* bh    = (const float*)d_in[9];
    const float* Wc_f  = (const float*)d_in[10];
    const float* bc    = (const float*)d_in[11];
    float* out = (float*)d_out;

    char* ws = (char*)d_ws;
    size_t off = 0;
    auto alloc = [&](size_t bytes) -> char* {
        off = (off + 255) & ~(size_t)255;
        char* p = ws + off;
        off += bytes;
        return p;
    };
    __bf16* Wih_b  = (__bf16*)alloc((size_t)NL * NG * ND * 2);
    __bf16* Whh_b  = (__bf16*)alloc((size_t)NL * NG * NH * 2);
    __bf16* Wo_b   = (__bf16*)alloc((size_t)NH * 2 * NH * 2);
    __bf16* Wh_b   = (__bf16*)alloc((size_t)NH * 2 * NH * 2);
    __bf16* Wc_b   = (__bf16*)alloc((size_t)NH * 2 * NH * 2);
    float*  biasc  = (float*) alloc((size_t)NL * NG * 4);
    __bf16* xbf    = (__bf16*)alloc((size_t)NT * NB * ND * 2);
    __bf16* ring_b = (__bf16*)alloc((size_t)2 * NL * 2 * NB * NH * 2);
    float*  ring_f = (float*) alloc((size_t)2 * NL * 2 * NB * NH * 4);
    __bf16* hbuf   = (__bf16*)alloc((size_t)2 * NL * 2 * NB * NH * 2);
    __bf16* outcat = (__bf16*)alloc((size_t)NT * NB * 2 * NH * 2);
    __bf16* hcat   = (__bf16*)alloc((size_t)NL * NB * 2 * NH * 2);
    __bf16* ccat   = (__bf16*)alloc((size_t)NL * NB * 2 * NH * 2);
    unsigned* bar  = (unsigned*)alloc(4096);

    auto launch_cvt = [&](const float* s, __bf16* d, size_t n) {
        size_t n4 = n / 4;
        int blocks = (int)((n4 + 255) / 256);
        if (blocks > 2048) blocks = 2048;
        k_cvt<<<blocks, 256, 0, stream>>>(s, d, n4);
    };
    launch_cvt(Wih_f, Wih_b, (size_t)NL * NG * ND);
    launch_cvt(Whh_f, Whh_b, (size_t)NL * NG * NH);
    launch_cvt(Wo_f,  Wo_b,  (size_t)2 * NH * NH);
    launch_cvt(Wh_f,  Wh_b,  (size_t)2 * NH * NH);
    launch_cvt(Wc_f,  Wc_b,  (size_t)2 * NH * NH);
    k_bias<<<(NL * NG) / 256, 256, 0, stream>>>(bih, bhh, biasc, NL * NG);
    k_embed<<<NT * NB, 256, 0, stream>>>(enc, emb, xbf);
    // h state + barrier counters must be zeroed EVERY launch (graph replays
    // leave final state; barrier epochs are monotonic within one launch).
    hipMemsetAsync(hbuf, 0, (size_t)2 * NL * 2 * NB * NH * 2, stream);
    hipMemsetAsync(bar, 0, 4096, stream);

    void* kargs[] = {
        (void*)&xbf, (void*)&Wih_b, (void*)&Whh_b, (void*)&biasc,
        (void*)&ring_b, (void*)&ring_f, (void*)&hbuf,
        (void*)&outcat, (void*)&hcat, (void*)&ccat, (void*)&bar };
    hipLaunchCooperativeKernel((const void*)k_lstm, dim3(256), dim3(512),
                               kargs, 0, stream);

    k_proj<<<(NT * NB / 64) * 16, 256, 0, stream>>>(outcat, Wo_b, bo, out, NT * NB, 0);
    k_proj<<<(NL * NB / 64) * 16, 256, 0, stream>>>(hcat, Wh_b, bh,
        out + (size_t)NB * NT * NH, NL * NB, 1);
    k_proj<<<(NL * NB / 64) * 16, 256, 0, stream>>>(ccat, Wc_b, bc,
        out + (size_t)NB * NT * NH + (size_t)NL * NB * NH, NL * NB, 1);
}

// Round 18
// 7138.222 us; speedup vs baseline: 1.4750x; 1.0451x over previous
//
#include <hip/hip_runtime.h>
#include <hip/hip_bf16.h>

// Bidirectional 4-layer residual LSTM encoder, MI355X (gfx950).
// R21: R20/R17 k_lstm UNTOUCHED (reproduced best: ~6900 us kernel).
// Only change: k_proj retiled from 64x64 to 64x256 per block (4 n-tiles
// of 16 per wave, acc[4][4]=64 VGPR). A-re-reads drop 16x -> 4x; the
// outcat GEMM tail was A-traffic bound (~1 GB pulled from LLC = ~300 us).
// Grid (M/64)x4; consecutive bids = same m-tile on different XCDs.
// k_lstm structure (proven): persistent cooperative kernel, weights
// pinned in 128 VGPR/wave, XCD-local layer mapping, cached A-loads,
// coalesced 16B sc0sc1 write-through stores, 2-level agent-atomic tree
// barrier, acquire-only buffer_inv sc1 after the release poll.

typedef __bf16 bf16x8 __attribute__((ext_vector_type(8)));
typedef __bf16 bf16x4 __attribute__((ext_vector_type(4)));
typedef float  f32x4  __attribute__((ext_vector_type(4)));
typedef float  f32x2  __attribute__((ext_vector_type(2)));
typedef int    i32x4  __attribute__((ext_vector_type(4)));

constexpr int NB = 64;    // batch
constexpr int NT = 256;   // time
constexpr int ND = 1024;  // embed dim
constexpr int NH = 1024;  // hidden
constexpr int NL = 4;     // layers
constexpr int NG = 4096;  // 4*NH gate rows

// ---- LLC-coherent coalesced store (write-through past L2) ----------------
__device__ __forceinline__ void st_b128_sc(void* p, i32x4 v) {
    asm volatile("global_store_dwordx4 %0, %1, off sc0 sc1" :: "v"(p), "v"(v) : "memory");
}
__device__ __forceinline__ float sigmoidf_fast(float x) {
    return 1.f / (1.f + __expf(-x));
}
__device__ __forceinline__ float tanhf_fast(float x) {
    return 1.f - 2.f / (__expf(2.f * x) + 1.f);   // exact at +-inf, ~1e-6 rel
}

// ---------------------------------------------------------------------------
// Persistent kernel. Grid: 4 layers x 64 cb = 256 blocks (1/CU). Block:
// 512 threads = 8 waves. Wave w: mat = w>>2 (0: Wih, 1: Whh), k0 = (w&3)*256.
// Layer mapping: layer = (bid&7)>>1, cb = ((bid>>3)<<1)|(bid&1) -> layer l
// occupies XCDs {2l, 2l+1} under the bid%8 round-robin dispatch.
// Weight regs: bf16x8 wreg[4 gates][8 ch]. Per step, per dir: acc[4 m][4 n]
// over M=64 batch x N=64 gate-cols, partials -> gbuf (XOR-swizzled) ->
// pointwise LSTM -> LDS staging -> coalesced 16B sc store pass.
// C/D frag (m89): row(batch)=(l>>4)*4+r (+16m), col=l&15.
// Barrier (uint idx): leaves at 32*(bid&15), root at 512, rel at 544.
// Coherence: cached A-reads made safe by `buffer_inv sc1` after the
// barrier poll (stores are sc write-through -> caches never dirty; only
// stale-line invalidation needed).
// ---------------------------------------------------------------------------
__global__ __launch_bounds__(512, 2) void k_lstm(
    const __bf16* __restrict__ xbf,     // [NT][NB][ND]
    const __bf16* __restrict__ Wih,     // [NL][NG][ND] bf16
    const __bf16* __restrict__ Whh,     // [NL][NG][NH] bf16
    const float*  __restrict__ biasc,   // [NL][NG] (b_ih+b_hh)
    __bf16* __restrict__ ring_b,        // [2*NL][2][NB][NH] layer input (bf16)
    float*  __restrict__ ring_f,        // [2*NL][2][NB][NH] layer input (f32)
    __bf16* __restrict__ hbuf,          // [2*NL][2][NB][NH] h ping-pong
    __bf16* __restrict__ outcat,        // [NT][NB][2*NH]
    __bf16* __restrict__ hcat,          // [NL*NB][2*NH] final h
    __bf16* __restrict__ ccat,          // [NL*NB][2*NH] final c
    unsigned* __restrict__ bar)         // barrier state (zeroed per launch)
{
    const int layer = (blockIdx.x & 7) >> 1;                    // XCD-local
    const int cb    = ((blockIdx.x >> 3) << 1) | (blockIdx.x & 1);
    const int tid   = threadIdx.x;
    const int w     = tid >> 6;          // 0..7
    const int mat   = w >> 2;            // 0: x-part (Wih), 1: h-part (Whh)
    const int k0    = (w & 3) * 256;     // K-slice within the 1024 of this mat
    const int lane  = tid & 63;
    const int lrow  = lane & 15;
    const int lk    = (lane >> 4) << 3;
    const int g4r   = (lane >> 4) << 2;  // row base within 16-row frag
    const size_t bh = (size_t)NB * NH;

    // --- persistent weights: 64 rows x 256 K bf16 = 128 VGPRs/wave ---
    bf16x8 wreg[4][8];
    {
        const __bf16* Bp = (mat ? Whh : Wih)
            + ((size_t)layer * NG + cb * 16 + lrow) * 1024 + k0 + lk;
        #pragma unroll
        for (int n = 0; n < 4; ++n)
            #pragma unroll
            for (int ch = 0; ch < 8; ++ch)
                wreg[n][ch] = *(const bf16x8*)(Bp + (size_t)n * NH * 1024 + ch * 32);
    }

    // --- per-thread persistent bias (n = tid&15 is this thread's col) ---
    float bias4[4];
    #pragma unroll
    for (int g = 0; g < 4; ++g)
        bias4[g] = biasc[(size_t)layer * NG + g * NH + cb * 16 + (tid & 15)];

    // --- per-thread persistent c state: [d][cell], cells = rows bp, bp+1 ---
    float c00 = 0.f, c01 = 0.f, c10 = 0.f, c11 = 0.f;

    // transposed partial buffer: [wave][gate][col16][row64], rows XOR-swizzled
    __shared__ __align__(16) float gbuf[8][4][16][64];   // 128 KB
    // output staging for coalesced stores (8 KB)
    __shared__ __align__(16) __bf16 sh_h[64][16];        // h  (bf16)
    __shared__ __align__(16) float  sh_f[64][16];        // residual (f32)
    __shared__ __align__(16) __bf16 sh_c[64][16];        // c  (bf16, final step)

    unsigned* leaf = bar + 32 * (blockIdx.x & 15);
    unsigned* root = bar + 512;
    unsigned* rel  = bar + 544;

    const int n_  = tid & 15;            // this thread's column within cb
    const int col = cb * 16 + n_;
    const int bp  = (tid >> 4) << 1;     // even batch row; cells (bp, bp+1)
    const int sw  = (n_ & 7) << 2;

    for (int gs = 0; gs < NT + NL - 1; ++gs) {
        const int tau = gs - layer;
        if (tau >= 0 && tau < NT) {
            #pragma unroll 1
            for (int d = 0; d < 2; ++d) {
                const int tt = d ? NT - 1 - tau : tau;
                const size_t ul = (size_t)(d * NL + layer);
                const size_t rbase = (ul * 2 + (tau & 1)) * bh;

                // residual inputs: produced last step, inv-fresh -> cached
                // loads issued first; latency hides under the GEMM.
                float inp0, inp1;
                if (layer == 0) {
                    inp0 = (float)xbf[(size_t)tt * NB * ND + (size_t)bp * ND + col];
                    inp1 = (float)xbf[(size_t)tt * NB * ND + (size_t)(bp + 1) * ND + col];
                } else {
                    inp0 = ring_f[rbase + (size_t)bp * NH + col];
                    inp1 = ring_f[rbase + (size_t)(bp + 1) * NH + col];
                }

                const __bf16* Ap;
                if (mat == 0)
                    Ap = (layer == 0) ? (xbf + (size_t)tt * NB * ND)
                                      : (ring_b + rbase);
                else
                    Ap = hbuf + (ul * 2 + ((tau + 1) & 1)) * bh;
                Ap += (size_t)lrow * 1024 + k0 + lk;

                // cached A-loads: this XCD's L2 serves the 32 co-located
                // blocks of this layer; compiler software-pipelines chunks.
                f32x4 acc[4][4] = {};   // [m][gate]
                #pragma unroll
                for (int ch = 0; ch < 8; ++ch) {
                    bf16x8 av[4];
                    #pragma unroll
                    for (int m = 0; m < 4; ++m)
                        av[m] = *(const bf16x8*)(Ap + (size_t)m * 16384 + ch * 32);
                    #pragma unroll
                    for (int n = 0; n < 4; ++n)
                        #pragma unroll
                        for (int m = 0; m < 4; ++m)
                            acc[m][n] = __builtin_amdgcn_mfma_f32_16x16x32_bf16(
                                av[m], wreg[n][ch], acc[m][n], 0, 0, 0);
                }

                // partials -> LDS as f32x4 (4 consecutive batch rows), swizzled
                #pragma unroll
                for (int n = 0; n < 4; ++n)
                    #pragma unroll
                    for (int m = 0; m < 4; ++m) {
                        const int row = (m * 16 + g4r) ^ ((lrow & 7) << 2);
                        *(f32x4*)&gbuf[w][n][lrow][row] = acc[m][n];
                    }
                __syncthreads();

                // fused LSTM pointwise: 2 adjacent cells/thread, f32x2 reduce
                {
                    const int swb = bp ^ sw;     // even; pair (swb, swb+1)
                    float g0[4], g1[4];
                    #pragma unroll
                    for (int g = 0; g < 4; ++g) {
                        float s0 = bias4[g], s1 = bias4[g];
                        #pragma unroll
                        for (int q = 0; q < 8; ++q) {
                            const f32x2 v = *(const f32x2*)&gbuf[q][g][n_][swb];
                            s0 += v[0]; s1 += v[1];
                        }
                        g0[g] = s0; g1[g] = s1;
                    }
                    const float cp0 = d ? c10 : c00;
                    const float cp1 = d ? c11 : c01;
                    const float si0 = sigmoidf_fast(g0[0]);
                    const float sf0 = sigmoidf_fast(g0[1]);
                    const float so0 = sigmoidf_fast(g0[3]);
                    const float tg0 = tanhf_fast(g0[2]);
                    const float cn0 = sf0 * cp0 + si0 * tg0;
                    const float hn0 = so0 * tanhf_fast(cn0);
                    const float si1 = sigmoidf_fast(g1[0]);
                    const float sf1 = sigmoidf_fast(g1[1]);
                    const float so1 = sigmoidf_fast(g1[3]);
                    const float tg1 = tanhf_fast(g1[2]);
                    const float cn1 = sf1 * cp1 + si1 * tg1;
                    const float hn1 = so1 * tanhf_fast(cn1);
                    if (d) { c10 = cn0; c11 = cn1; }
                    else   { c00 = cn0; c01 = cn1; }

                    // stage to LDS (coalesced global store pass follows)
                    sh_h[bp][n_]     = (__bf16)hn0;
                    sh_h[bp + 1][n_] = (__bf16)hn1;
                    sh_f[bp][n_]     = inp0 + hn0;
                    sh_f[bp + 1][n_] = inp1 + hn1;
                    if (tau == NT - 1) {
                        sh_c[bp][n_]     = (__bf16)cn0;
                        sh_c[bp + 1][n_] = (__bf16)cn1;
                    }
                }
                __syncthreads();

                // ---- coalesced 16B sc store pass ----
                if (tid < 128) {
                    const int r = tid >> 1, sg = tid & 1;
                    const i32x4 v = *(const i32x4*)&sh_h[r][sg * 8];
                    st_b128_sc(hbuf + rbase + (size_t)r * NH + cb * 16 + sg * 8, v);
                    if (tau == NT - 1) {
                        st_b128_sc(hcat + ((size_t)layer * NB + r) * 2048
                                        + (size_t)d * NH + cb * 16 + sg * 8, v);
                    }
                } else if (tid < 384) {
                    if (layer < NL - 1) {
                        const int t2 = tid - 128;
                        const int r = t2 >> 2, sg = t2 & 3;
                        const i32x4 v = *(const i32x4*)&sh_f[r][sg * 4];
                        st_b128_sc(ring_f + ((ul + 1) * 2 + (tau & 1)) * bh
                                          + (size_t)r * NH + cb * 16 + sg * 4, v);
                    }
                    if (tau == NT - 1 && tid < 256) {
                        const int t2 = tid - 128;
                        const int r = t2 >> 1, sg = t2 & 1;
                        const i32x4 v = *(const i32x4*)&sh_c[r][sg * 8];
                        st_b128_sc(ccat + ((size_t)layer * NB + r) * 2048
                                        + (size_t)d * NH + cb * 16 + sg * 8, v);
                    }
                } else {
                    const int t3 = tid - 384;
                    const int r = t3 >> 1, sg = t3 & 1;
                    bf16x8 o;
                    #pragma unroll
                    for (int j = 0; j < 8; ++j) o[j] = (__bf16)sh_f[r][sg * 8 + j];
                    const i32x4 v = __builtin_bit_cast(i32x4, o);
                    if (layer < NL - 1)
                        st_b128_sc(ring_b + ((ul + 1) * 2 + (tau & 1)) * bh
                                          + (size_t)r * NH + cb * 16 + sg * 8, v);
                    else
                        st_b128_sc(outcat + ((size_t)tt * NB + r) * 2048
                                          + (size_t)d * NH + cb * 16 + sg * 8, v);
                }

                if (d == 1)   // drain asm sc stores once per step, pre-barrier
                    asm volatile("s_waitcnt vmcnt(0)" ::: "memory");
                __syncthreads();
            }
        }

        // ---- grid barrier: two-level agent-atomic tree (R9/R12-proven) ----
        if (gs < NT + NL - 2) {
            __syncthreads();
            if (tid == 0) {
                const unsigned e1 = (unsigned)(gs + 1);
                const unsigned old = __hip_atomic_fetch_add(
                    leaf, 1u, __ATOMIC_RELAXED, __HIP_MEMORY_SCOPE_AGENT);
                if (old == 16u * e1 - 1u) {
                    const unsigned r = __hip_atomic_fetch_add(
                        root, 1u, __ATOMIC_RELAXED, __HIP_MEMORY_SCOPE_AGENT);
                    if (r == 16u * e1 - 1u)
                        __hip_atomic_store(rel, e1, __ATOMIC_RELAXED,
                                           __HIP_MEMORY_SCOPE_AGENT);
                }
                while (__hip_atomic_load(rel, __ATOMIC_RELAXED,
                                         __HIP_MEMORY_SCOPE_AGENT) < e1)
                    __builtin_amdgcn_s_sleep(2);
                // acquire-only: invalidate stale L1/L2 lines (caches are
                // never dirty - all stores are sc0sc1 write-through), so
                // the wbl2 half of __threadfence is unnecessary.
                asm volatile("buffer_inv sc1" ::: "memory");
            }
            __syncthreads();
        }
    }
}

// ---------------------------------------------------------------------------
// Projection GEMM: Dst = A[M][2048] @ W[1024][2048]^T + bias.
// R21 tiling: block = 64 rows x 256 cols (4 waves x 4 n-tiles of 16,
// acc[4][4]); grid (M/64) x 4. A re-read 16x -> 4x vs the 64x64 tiling.
// mode 0: A rows are (t*NB+b), write Dst[(b*NT+t)*NH + col]. mode 1: direct.
// ---------------------------------------------------------------------------
__global__ __launch_bounds__(256) void k_proj(
    const __bf16* __restrict__ A, const __bf16* __restrict__ W,
    const float* __restrict__ bias, float* __restrict__ Dst,
    int M, int mode)
{
    const int nblk = blockIdx.x & 3;     // 256-col span
    const int mblk = blockIdx.x >> 2;
    const int tid  = threadIdx.x;
    const int w    = tid >> 6;
    const int lane = tid & 63;
    const int lrow = lane & 15;
    const int lk   = (lane >> 4) << 3;
    const int m0   = mblk * 64;
    const int nb   = nblk * 256 + w * 16;   // wave's n-tile j at nb + j*64

    f32x4 acc[4][4] = {};   // [m][j]
    for (int k0 = 0; k0 < 2048; k0 += 32) {
        const int kc = k0 + lk;
        bf16x8 bv[4];
        #pragma unroll
        for (int j = 0; j < 4; ++j)
            bv[j] = *(const bf16x8*)(W + (size_t)(nb + j * 64 + lrow) * 2048 + kc);
        #pragma unroll
        for (int m = 0; m < 4; ++m) {
            const bf16x8 av = *(const bf16x8*)(A + (size_t)(m0 + m * 16 + lrow) * 2048 + kc);
            #pragma unroll
            for (int j = 0; j < 4; ++j)
                acc[m][j] = __builtin_amdgcn_mfma_f32_16x16x32_bf16(av, bv[j], acc[m][j], 0, 0, 0);
        }
    }
    #pragma unroll
    for (int m = 0; m < 4; ++m) {
        #pragma unroll
        for (int j = 0; j < 4; ++j) {
            #pragma unroll
            for (int r = 0; r < 4; ++r) {
                const int row = m0 + m * 16 + ((lane >> 4) << 2) + r;
                const int col = nb + j * 64 + lrow;
                const float v = acc[m][j][r] + bias[col];
                if (mode == 0) {
                    const int tt = row >> 6, bb = row & 63;
                    Dst[((size_t)bb * NT + tt) * NH + col] = v;
                } else {
                    Dst[(size_t)row * NH + col] = v;
                }
            }
        }
    }
}

__global__ void k_embed(const int* __restrict__ enc, const float* __restrict__ emb,
                        __bf16* __restrict__ xbf)
{
    const int r = blockIdx.x;          // t*NB + b
    const int t = r >> 6;
    const int b = r & 63;
    const int id = enc[b * NT + t];
    const float4 v = ((const float4*)(emb + (size_t)id * ND))[threadIdx.x];
    bf16x4 o;
    o[0] = (__bf16)v.x; o[1] = (__bf16)v.y; o[2] = (__bf16)v.z; o[3] = (__bf16)v.w;
    ((bf16x4*)(xbf + (size_t)r * ND))[threadIdx.x] = o;
}

__global__ void k_cvt(const float* __restrict__ src, __bf16* __restrict__ dst, size_t n4)
{
    size_t i = (size_t)blockIdx.x * blockDim.x + threadIdx.x;
    const size_t stride = (size_t)gridDim.x * blockDim.x;
    for (; i < n4; i += stride) {
        const float4 v = ((const float4*)src)[i];
        bf16x4 o;
        o[0] = (__bf16)v.x; o[1] = (__bf16)v.y; o[2] = (__bf16)v.z; o[3] = (__bf16)v.w;
        ((bf16x4*)dst)[i] = o;
    }
}

__global__ void k_bias(const float* __restrict__ a, const float* __restrict__ b,
                       float* __restrict__ o, int n)
{
    const int i = blockIdx.x * blockDim.x + threadIdx.x;
    if (i < n) o[i] = a[i] + b[i];
}

extern "C" void kernel_launch(void* const* d_in, const int* in_sizes, int n_in,
                              void* d_out, int out_size, void* d_ws, size_t ws_size,
                              hipStream_t stream)
{
    const int*   enc   = (const int*)  d_in[0];
    const float* emb   = (const float*)d_in[1];
    const float* Wih_f = (const float*)d_in[2];
    const float* Whh_f = (const float*)d_in[3];
    const float* bih   = (const float*)d_in[4];
    const float* bhh   = (const float*)d_in[5];
    const float* Wo_f  = (const float*)d_in[6];
    const float* bo    = (const float*)d_in[7];
    const float* Wh_f  = (const float*)d_in[8];
    const float* bh    = (const float*)d_in[9];
    const float* Wc_f  = (const float*)d_in[10];
    const float* bc    = (const float*)d_in[11];
    float* out = (float*)d_out;

    char* ws = (char*)d_ws;
    size_t off = 0;
    auto alloc = [&](size_t bytes) -> char* {
        off = (off + 255) & ~(size_t)255;
        char* p = ws + off;
        off += bytes;
        return p;
    };
    __bf16* Wih_b  = (__bf16*)alloc((size_t)NL * NG * ND * 2);
    __bf16* Whh_b  = (__bf16*)alloc((size_t)NL * NG * NH * 2);
    __bf16* Wo_b   = (__bf16*)alloc((size_t)NH * 2 * NH * 2);
    __bf16* Wh_b   = (__bf16*)alloc((size_t)NH * 2 * NH * 2);
    __bf16* Wc_b   = (__bf16*)alloc((size_t)NH * 2 * NH * 2);
    float*  biasc  = (float*) alloc((size_t)NL * NG * 4);
    __bf16* xbf    = (__bf16*)alloc((size_t)NT * NB * ND * 2);
    __bf16* ring_b = (__bf16*)alloc((size_t)2 * NL * 2 * NB * NH * 2);
    float*  ring_f = (float*) alloc((size_t)2 * NL * 2 * NB * NH * 4);
    __bf16* hbuf   = (__bf16*)alloc((size_t)2 * NL * 2 * NB * NH * 2);
    __bf16* outcat = (__bf16*)alloc((size_t)NT * NB * 2 * NH * 2);
    __bf16* hcat   = (__bf16*)alloc((size_t)NL * NB * 2 * NH * 2);
    __bf16* ccat   = (__bf16*)alloc((size_t)NL * NB * 2 * NH * 2);
    unsigned* bar  = (unsigned*)alloc(4096);

    auto launch_cvt = [&](const float* s, __bf16* d, size_t n) {
        size_t n4 = n / 4;
        int blocks = (int)((n4 + 255) / 256);
        if (blocks > 2048) blocks = 2048;
        k_cvt<<<blocks, 256, 0, stream>>>(s, d, n4);
    };
    launch_cvt(Wih_f, Wih_b, (size_t)NL * NG * ND);
    launch_cvt(Whh_f, Whh_b, (size_t)NL * NG * NH);
    launch_cvt(Wo_f,  Wo_b,  (size_t)2 * NH * NH);
    launch_cvt(Wh_f,  Wh_b,  (size_t)2 * NH * NH);
    launch_cvt(Wc_f,  Wc_b,  (size_t)2 * NH * NH);
    k_bias<<<(NL * NG) / 256, 256, 0, stream>>>(bih, bhh, biasc, NL * NG);
    k_embed<<<NT * NB, 256, 0, stream>>>(enc, emb, xbf);
    // h state + barrier counters must be zeroed EVERY launch (graph replays
    // leave final state; barrier epochs are monotonic within one launch).
    hipMemsetAsync(hbuf, 0, (size_t)2 * NL * 2 * NB * NH * 2, stream);
    hipMemsetAsync(bar, 0, 4096, stream);

    void* kargs[] = {
        (void*)&xbf, (void*)&Wih_b, (void*)&Whh_b, (void*)&biasc,
        (void*)&ring_b, (void*)&ring_f, (void*)&hbuf,
        (void*)&outcat, (void*)&hcat, (void*)&ccat, (void*)&bar };
    hipLaunchCooperativeKernel((const void*)k_lstm, dim3(256), dim3(512),
                               kargs, 0, stream);

    k_proj<<<(NT * NB / 64) * 4, 256, 0, stream>>>(outcat, Wo_b, bo, out, NT * NB, 0);
    k_proj<<<(NL * NB / 64) * 4, 256, 0, stream>>>(hcat, Wh_b, bh,
        out + (size_t)NB * NT * NH, NL * NB, 1);
    k_proj<<<(NL * NB / 64) * 4, 256, 0, stream>>>(ccat, Wc_b, bc,
        out + (size_t)NB * NT * NH + (size_t)NL * NB * NH, NL * NB, 1);
}